// Round 6
// baseline (39.601 us; speedup 1.0000x reference)
//
#include <hip/hip_runtime.h>

// Zoom: out[b,c,t,f] = w*x[..., floor(f*k/n)] + (1-w)*x[..., floor(f*k/n)+1]
// Shape [8,16,256,1024] fp32; k, n runtime device scalars (k=2, n=3 here).
// R0 (67.8us): scalar global gathers -> TA/coalescer bound.
// R1 (68.5us): 4x row unroll, no change -> throughput (not latency) bound.
// R2 (39.8us): LDS staging + LDS gathers.
// R3 (40.5us): DMA staging + dbuf NEUTRAL -> TLP already hides latency.
// R4 (39.4us): compulsory-byte staging (684 words/row). 219MB/39.4us =
//   5.56 TB/s = 88% of m13 copy ceiling (6.29 TB/s). Gap = per-block fixed
//   cost (prologue divisions ~8% of 2960-cyc block lifetime) + barrier.
// R5: RU=8 (amortize prologue/barrier 2x; 32KB LDS, 5 blk/CU -- R1 showed
//   occupancy is not binding) + strength-reduced coefficients (2 int divides
//   instead of 4, incremental carry chain; 1/n reciprocal multiply).

typedef float f32x4 __attribute__((ext_vector_type(4)));

constexpr int F = 1024;          // last-dim size from reference shape
constexpr int VEC = 4;           // outputs per thread
constexpr int BLOCK = F / VEC;   // 256 threads = 4 waves: block covers a row
constexpr int RU = 8;            // rows per block (32 KB LDS)

__global__ __launch_bounds__(BLOCK) void zoom_kernel(
    const float* __restrict__ x,
    const int* __restrict__ kp,
    const int* __restrict__ np_,
    float* __restrict__ out,
    int nrows) {
  __shared__ float lds[RU][F];

  const int k = kp[0];
  const int n = np_[0];

  const int f0 = threadIdx.x * VEC;
  const int wv = threadIdx.x >> 6;   // wave id 0..3
  const int ln = threadIdx.x & 63;   // lane id

  // Loop-invariant interpolation coefficients, strength-reduced:
  // pos_j = f0*k + j*k; idx_j = pos_j / n.  Two divides total:
  //   q0,r0 = divmod(f0*k, n);  qk,rk = divmod(k, n)  (rk < n).
  // Step: r += rk; carry = r>=n; r -= carry*n; q += qk + carry.
  const float inv_n = 1.0f / (float)n;
  int q = (f0 * k) / n;
  int r = f0 * k - q * n;
  const int qk = k / n;
  const int rk = k - qk * n;

  int  idx0[VEC], idx1[VEC];
  float w0[VEC], w1[VEC];
#pragma unroll
  for (int j = 0; j < VEC; ++j) {
    const float w = 1.0f - (float)r * inv_n;
    const bool v0 = q < F;
    const bool v1 = (q + 1) < F;
    w0[j]   = v0 ? w : 0.0f;
    w1[j]   = v1 ? (1.0f - w) : 0.0f;
    idx0[j] = v0 ? q : 0;                      // clamped; weight already zeroed
    idx1[j] = v1 ? (q + 1) : (F - 1);
    r += rk;
    const int carry = (r >= n) ? 1 : 0;
    r -= carry ? n : 0;
    q += qk + carry;
  }

  // Highest source word referenced: floor((F-1)*k/n)+1 -> nwords needed.
  int nwords = ((F - 1) * k) / n + 2;
  if (nwords > F) nwords = F;
  // Stage in 256-word (1 KB) wave segments; last segment shifted to end
  // exactly at nwords (16B-aligned start; overlap re-reads L2-hot lines).
  const int segs = (nwords + 255) >> 8;          // 1..4
  int last_start = 0;
  if (nwords > 256) {
    last_start = (nwords - 256 + 3) & ~3;        // 16B-aligned, +256 >= nwords
  }
  const int nstage = RU * segs;

  const size_t row0 = (size_t)blockIdx.x * RU;

  // Stage: global_load_lds width-16 DMA (wave-uniform LDS base + lane*16B).
  for (int s = wv; s < nstage; s += 4) {
    const int rr  = s / segs;
    const int seg = s - rr * segs;
    const int start = (seg == segs - 1) ? last_start : seg * 256;
    size_t row = row0 + (size_t)rr;
    if (row >= (size_t)nrows) row = (size_t)nrows - 1;   // safe re-stage
    const float* gp = x + row * F + start + ln * 4;      // 16B aligned
    float* lp = &lds[rr][start];                         // wave-uniform base
    __builtin_amdgcn_global_load_lds(
        (const __attribute__((address_space(1))) void*)gp,
        (__attribute__((address_space(3))) void*)lp, 16, 0, 0);
  }
  __syncthreads();   // vmcnt(0) drain: all rows staged

  // Gather from LDS + nontemporal coalesced f32x4 store.
#pragma unroll
  for (int rr = 0; rr < RU; ++rr) {
    if (row0 + (size_t)rr >= (size_t)nrows) break;
    f32x4 v;
    v.x = w0[0] * lds[rr][idx0[0]] + w1[0] * lds[rr][idx1[0]];
    v.y = w0[1] * lds[rr][idx0[1]] + w1[1] * lds[rr][idx1[1]];
    v.z = w0[2] * lds[rr][idx0[2]] + w1[2] * lds[rr][idx1[2]];
    v.w = w0[3] * lds[rr][idx0[3]] + w1[3] * lds[rr][idx1[3]];
    __builtin_nontemporal_store(v, (f32x4*)(out + (row0 + (size_t)rr) * F + f0));
  }
}

extern "C" void kernel_launch(void* const* d_in, const int* in_sizes, int n_in,
                              void* d_out, int out_size, void* d_ws, size_t ws_size,
                              hipStream_t stream) {
  const float* x   = (const float*)d_in[0];
  const int*   kp  = (const int*)d_in[1];
  const int*   np_ = (const int*)d_in[2];
  float* out = (float*)d_out;

  const int total = in_sizes[0];        // 8*16*256*1024
  const int nrows = total / F;          // 32768

  const int grid = (nrows + RU - 1) / RU;   // 4096 blocks, one chunk each
  zoom_kernel<<<grid, BLOCK, 0, stream>>>(x, kp, np_, out, nrows);
}